// Round 6
// baseline (56.680 us; speedup 1.0000x reference)
//
#include <hip/hip_runtime.h>
#include <cstdint>

typedef float v2f __attribute__((ext_vector_type(2)));
typedef float v4f __attribute__((ext_vector_type(4)));

#define N_PRED 8192
#define N_GT   32768
#define BLK    256
#define HOFF   64.0f   // h = p.g - 0.5|g|^2 + 64 > 0 always (coords ~N(0,1))

// NN: PP=8 preds/thread, pred-chunk 2048 (4 pc) x gt-tile 256 (128 gc) = 512 blocks
#define NN_PP   8
#define NN_PCH  2048
#define NN_TILE 256
#define NN_NGC  128

// REP: PP=4, pred sub-chunk 1024 (8 s) x self-tile 256 (32 t) = 256 blocks
#define RP_PP   4
#define RP_PCH  1024
#define RP_TILE 256
#define RP_NT   32

// ws: u64 keys[8192] (64KB) | f32 repchunk[8192][32] (1MB) | f32 partials[32][3]
#define OFF_REP  65536
#define OFF_PART (OFF_REP + N_PRED * RP_NT * 4)

__device__ __forceinline__ v2f pk_fma(v2f a, v2f b, v2f c) {
    v2f d;
    asm("v_pk_fma_f32 %0, %1, %2, %3" : "=v"(d) : "v"(a), "v"(b), "v"(c));
    return d;
}
__device__ __forceinline__ float max3f(float a, float b, float c) {
    float d;
    asm("v_max3_f32 %0, %1, %2, %3" : "=v"(d) : "v"(a), "v"(b), "v"(c));
    return d;
}

// load 8 consecutive tile points (base kk, 16B-aligned) as 4 v2f per coord
#define LOAD8(kk, gx, gy, gz, gw)                                         \
    {                                                                     \
        const v4f xv0 = *(const v4f*)&sx[kk], xv1 = *(const v4f*)&sx[(kk) + 4]; \
        const v4f yv0 = *(const v4f*)&sy[kk], yv1 = *(const v4f*)&sy[(kk) + 4]; \
        const v4f zv0 = *(const v4f*)&sz[kk], zv1 = *(const v4f*)&sz[(kk) + 4]; \
        const v4f wv0 = *(const v4f*)&sw[kk], wv1 = *(const v4f*)&sw[(kk) + 4]; \
        gx[0] = __builtin_shufflevector(xv0, xv0, 0, 1);                  \
        gx[1] = __builtin_shufflevector(xv0, xv0, 2, 3);                  \
        gx[2] = __builtin_shufflevector(xv1, xv1, 0, 1);                  \
        gx[3] = __builtin_shufflevector(xv1, xv1, 2, 3);                  \
        gy[0] = __builtin_shufflevector(yv0, yv0, 0, 1);                  \
        gy[1] = __builtin_shufflevector(yv0, yv0, 2, 3);                  \
        gy[2] = __builtin_shufflevector(yv1, yv1, 0, 1);                  \
        gy[3] = __builtin_shufflevector(yv1, yv1, 2, 3);                  \
        gz[0] = __builtin_shufflevector(zv0, zv0, 0, 1);                  \
        gz[1] = __builtin_shufflevector(zv0, zv0, 2, 3);                  \
        gz[2] = __builtin_shufflevector(zv1, zv1, 0, 1);                  \
        gz[3] = __builtin_shufflevector(zv1, zv1, 2, 3);                  \
        gw[0] = __builtin_shufflevector(wv0, wv0, 0, 1);                  \
        gw[1] = __builtin_shufflevector(wv0, wv0, 2, 3);                  \
        gw[2] = __builtin_shufflevector(wv1, wv1, 0, 1);                  \
        gw[3] = __builtin_shufflevector(wv1, wv1, 2, 3);                  \
    }

// dot-product h for 8 points against broadcast pred q
#define DOT8(h, gx, gy, gz, gw, q)                                        \
    {                                                                     \
        _Pragma("unroll")                                                 \
        for (int _i = 0; _i < 4; ++_i) {                                  \
            v2f _t = pk_fma(PZ[q], gz[_i], gw[_i]);                       \
            _t = pk_fma(PY[q], gy[_i], _t);                               \
            h[_i] = pk_fma(PX[q], gx[_i], _t);                            \
        }                                                                 \
    }

// max of 8 values in h[4] (v2f) -> scalar
#define RED8(out, h)                                                      \
    {                                                                     \
        const float _m0 = max3f(h[0].x, h[0].y, h[1].x);                  \
        const float _m1 = max3f(h[1].y, h[2].x, h[2].y);                  \
        const float _m2 = fmaxf(h[3].x, h[3].y);                          \
        out = max3f(_m0, _m1, _m2);                                       \
    }

__global__ __launch_bounds__(256) void init_kernel(unsigned long long* __restrict__ keys) {
    const int i = blockIdx.x * blockDim.x + threadIdx.x;
    if (i < N_PRED) keys[i] = 0ull;
}

// ---- NN: exact argmax of h, tracked at 16-gt-group granularity;
//      cross-block merge via u64 atomicMax (tie -> smaller gt index). ----
__global__ __launch_bounds__(256) void nn_kernel(const float* __restrict__ pred,
                                                 const float* __restrict__ gt,
                                                 unsigned long long* __restrict__ keys) {
    __shared__ alignas(16) float sx[NN_TILE], sy[NN_TILE], sz[NN_TILE], sw[NN_TILE];
    const int pc = blockIdx.x >> 7;
    const int gc = blockIdx.x & (NN_NGC - 1);
    const int gbase = gc * NN_TILE;

    {
        const int k = threadIdx.x;                   // NN_TILE == BLK
        const int g = gbase + k;
        const float x = gt[g * 6 + 0], y = gt[g * 6 + 1], z = gt[g * 6 + 2];
        sx[k] = x; sy[k] = y; sz[k] = z;
        sw[k] = fmaf(-0.5f, fmaf(z, z, fmaf(y, y, x * x)), HOFF);
    }
    __syncthreads();

    const int pbase = pc * NN_PCH + threadIdx.x;
    v2f PX[NN_PP], PY[NN_PP], PZ[NN_PP];
    float best[NN_PP];
    unsigned bk[NN_PP];
#pragma unroll
    for (int q = 0; q < NN_PP; ++q) {
        const int p = pbase + q * BLK;
        const float x = pred[p * 6 + 0], y = pred[p * 6 + 1], z = pred[p * 6 + 2];
        v2f vx; vx.x = x; vx.y = x; PX[q] = vx;
        v2f vy; vy.x = y; vy.y = y; PY[q] = vy;
        v2f vz; vz.x = z; vz.y = z; PZ[q] = vz;
        best[q] = 0.0f;                              // h > 0 always
        bk[q] = 0u;
    }

#pragma unroll 1
    for (int k = 0; k < NN_TILE; k += 16) {
        v2f gx[4], gy[4], gz[4], gw[4];
        float pa[NN_PP];
        LOAD8(k, gx, gy, gz, gw);
#pragma unroll
        for (int q = 0; q < NN_PP; ++q) {
            v2f h[4];
            DOT8(h, gx, gy, gz, gw, q);
            RED8(pa[q], h);
        }
        LOAD8(k + 8, gx, gy, gz, gw);
#pragma unroll
        for (int q = 0; q < NN_PP; ++q) {
            v2f h[4];
            DOT8(h, gx, gy, gz, gw, q);
            float pb;
            RED8(pb, h);
            const float gm = fmaxf(pa[q], pb);
            if (gm > best[q]) { best[q] = gm; bk[q] = (unsigned)k; }  // first group wins ties
        }
    }

#pragma unroll
    for (int q = 0; q < NN_PP; ++q) {
        const unsigned gidx = (unsigned)gbase + bk[q];          // 16-aligned group base
        const unsigned long long key =
            ((unsigned long long)__float_as_uint(best[q]) << 32) |
            (unsigned long long)(~gidx);                        // tie -> smaller index
        atomicMax(&keys[pbase + q * BLK], key);
    }
}

// ---- Repulsion: exact per-(pred, tile) max of h, j != i. Value only. ----
__global__ __launch_bounds__(256) void rep_kernel(const float* __restrict__ pred,
                                                  float* __restrict__ repchunk) {
    __shared__ alignas(16) float sx[RP_TILE], sy[RP_TILE], sz[RP_TILE], sw[RP_TILE];
    const int s = blockIdx.x >> 5;
    const int t = blockIdx.x & (RP_NT - 1);
    const int tbase = t * RP_TILE;

    {
        const int k = threadIdx.x;                   // RP_TILE == BLK
        const int j = tbase + k;
        const float x = pred[j * 6 + 0], y = pred[j * 6 + 1], z = pred[j * 6 + 2];
        sx[k] = x; sy[k] = y; sz[k] = z;
        sw[k] = fmaf(-0.5f, fmaf(z, z, fmaf(y, y, x * x)), HOFF);
    }
    __syncthreads();

    const int pbase = s * RP_PCH + threadIdx.x;
    v2f PX[RP_PP], PY[RP_PP], PZ[RP_PP];
    float best[RP_PP];
    int selfk[RP_PP];
#pragma unroll
    for (int q = 0; q < RP_PP; ++q) {
        const int p = pbase + q * BLK;
        const float x = pred[p * 6 + 0], y = pred[p * 6 + 1], z = pred[p * 6 + 2];
        v2f vx; vx.x = x; vx.y = x; PX[q] = vx;
        v2f vy; vy.x = y; vy.y = y; PY[q] = vy;
        v2f vz; vz.x = z; vz.y = z; PZ[q] = vz;
        best[q] = -3.0e38f;
        selfk[q] = p - tbase;    // in [0,RP_TILE) only for the matching diagonal sub-chunk
    }

    const bool diag = (t >= s * 4) && (t < s * 4 + 4);
    if (diag) {
#pragma unroll 1
        for (int k = 0; k < RP_TILE; k += 8) {
            v2f gx[4], gy[4], gz[4], gw[4];
            LOAD8(k, gx, gy, gz, gw);
#pragma unroll
            for (int q = 0; q < RP_PP; ++q) {
                v2f h[4];
                DOT8(h, gx, gy, gz, gw, q);
#pragma unroll
                for (int i = 0; i < 4; ++i) {
                    const int kb = k + 2 * i;
                    h[i].x = (kb == selfk[q]) ? -3.0e38f : h[i].x;
                    h[i].y = (kb + 1 == selfk[q]) ? -3.0e38f : h[i].y;
                }
                float m;
                RED8(m, h);
                best[q] = fmaxf(best[q], m);
            }
        }
    } else {
#pragma unroll 1
        for (int k = 0; k < RP_TILE; k += 8) {
            v2f gx[4], gy[4], gz[4], gw[4];
            LOAD8(k, gx, gy, gz, gw);
#pragma unroll
            for (int q = 0; q < RP_PP; ++q) {
                v2f h[4];
                DOT8(h, gx, gy, gz, gw, q);
                float m;
                RED8(m, h);
                best[q] = fmaxf(best[q], m);
            }
        }
    }

#pragma unroll
    for (int q = 0; q < RP_PP; ++q)
        repchunk[(pbase + q * BLK) * RP_NT + t] = best[q];
}

// ---- finalize: 16-point group rescan (bitwise-identical fma chain) + losses ----
__global__ __launch_bounds__(256) void finalize_kernel(const float* __restrict__ pred,
                                                       const float* __restrict__ gt,
                                                       const unsigned long long* __restrict__ keys,
                                                       const float* __restrict__ repchunk,
                                                       float* __restrict__ partials) {
    const int p = blockIdx.x * blockDim.x + threadIdx.x;
    const float px = pred[p * 6 + 0], py = pred[p * 6 + 1], pz = pred[p * 6 + 2];

    const unsigned long long key = keys[p];
    const int gb = (int)(~(unsigned)(key & 0xFFFFFFFFull));

    float bh = -3.0e38f;
    int j = gb;
#pragma unroll
    for (int i = 0; i < 16; ++i) {
        const int g = gb + i;
        const float x = gt[g * 6 + 0], y = gt[g * 6 + 1], z = gt[g * 6 + 2];
        const float w = fmaf(-0.5f, fmaf(z, z, fmaf(y, y, x * x)), HOFF);
        const float h = fmaf(px, x, fmaf(py, y, fmaf(pz, z, w)));
        if (h > bh) { bh = h; j = g; }               // first max = numpy argmin
    }

    const float gx = gt[j * 6 + 0], gy = gt[j * 6 + 1], gz = gt[j * 6 + 2];
    const float dx = px - gx, dy = py - gy, dz = pz - gz;
    float att = dx * dx + dy * dy + dz * dz;

    const float pnx = pred[p * 6 + 3], pny = pred[p * 6 + 4], pnz = pred[p * 6 + 5];
    const float gnx = gt[j * 6 + 3],   gny = gt[j * 6 + 4],   gnz = gt[j * 6 + 5];
    const float pl = fmaxf(sqrtf(pnx * pnx + pny * pny + pnz * pnz), 1e-5f);
    const float gl = fmaxf(sqrtf(gnx * gnx + gny * gny + gnz * gnz), 1e-5f);
    float nrm = 1.0f - (pnx * gnx + pny * gny + pnz * gnz) / (pl * gl);

    float rm = -3.0e38f;
    const v4f* rc = (const v4f*)&repchunk[p * RP_NT];
#pragma unroll
    for (int i = 0; i < RP_NT / 4; ++i) {
        const v4f v = rc[i];
        rm = fmaxf(rm, fmaxf(fmaxf(v.x, v.y), fmaxf(v.z, v.w)));
    }
    // min d^2 = |p|^2 + 2*HOFF - 2*h_max
    const float pp2 = px * px + py * py + pz * pz;
    float d2 = fmaf(-2.0f, rm, pp2 + 2.0f * HOFF);
    d2 = fmaxf(d2, 0.0f);
    const float xa = 100.0f * (0.3f - sqrtf(d2));
    const float sp = fmaxf(xa, 0.0f) + log1pf(expf(-fabsf(xa)));
    float rep = sp * sp;

#pragma unroll
    for (int off = 32; off > 0; off >>= 1) {
        att += __shfl_down(att, off, 64);
        nrm += __shfl_down(nrm, off, 64);
        rep += __shfl_down(rep, off, 64);
    }

    __shared__ float red[4][3];
    const int wave = threadIdx.x >> 6;
    const int lane = threadIdx.x & 63;
    if (lane == 0) { red[wave][0] = att; red[wave][1] = nrm; red[wave][2] = rep; }
    __syncthreads();
    if (threadIdx.x < 3) {
        partials[blockIdx.x * 3 + threadIdx.x] =
            red[0][threadIdx.x] + red[1][threadIdx.x] +
            red[2][threadIdx.x] + red[3][threadIdx.x];
    }
}

__global__ void combine_kernel(const float* __restrict__ partials, float* __restrict__ out) {
    const int lane = threadIdx.x;                    // 64 threads
    float a = 0.f, n = 0.f, r = 0.f;
    if (lane < 32) {
        a = partials[lane * 3 + 0];
        n = partials[lane * 3 + 1];
        r = partials[lane * 3 + 2];
    }
#pragma unroll
    for (int off = 32; off > 0; off >>= 1) {
        a += __shfl_down(a, off, 64);
        n += __shfl_down(n, off, 64);
        r += __shfl_down(r, off, 64);
    }
    if (lane == 0)
        out[0] = a / (float)(N_PRED * 3) + r / (float)N_PRED + 10.0f * (n / (float)N_PRED);
}

extern "C" void kernel_launch(void* const* d_in, const int* in_sizes, int n_in,
                              void* d_out, int out_size, void* d_ws, size_t ws_size,
                              hipStream_t stream) {
    const float* pred = (const float*)d_in[0];   // (8192, 6)
    const float* gt   = (const float*)d_in[3];   // (32768, 6)
    float* out = (float*)d_out;
    char* ws = (char*)d_ws;

    unsigned long long* keys = (unsigned long long*)ws;       // 64 KB
    float* repchunk = (float*)(ws + OFF_REP);                 // 1 MB
    float* partials = (float*)(ws + OFF_PART);                // 32*3 floats

    init_kernel<<<N_PRED / 256, 256, 0, stream>>>(keys);
    nn_kernel<<<(N_PRED / NN_PCH) * NN_NGC, BLK, 0, stream>>>(pred, gt, keys);
    rep_kernel<<<(N_PRED / RP_PCH) * RP_NT, BLK, 0, stream>>>(pred, repchunk);
    finalize_kernel<<<N_PRED / 256, 256, 0, stream>>>(pred, gt, keys, repchunk, partials);
    combine_kernel<<<1, 64, 0, stream>>>(partials, out);
}

// Round 7
// 55.441 us; speedup vs baseline: 1.0223x; 1.0223x over previous
//
#include <hip/hip_runtime.h>
#include <cstdint>

typedef float v2f __attribute__((ext_vector_type(2)));
typedef float v4f __attribute__((ext_vector_type(4)));

#define N_PRED 8192
#define N_GT   32768
#define BLK    256
#define HOFF   64.0f   // h = p.g - 0.5|g|^2 + 64 > 0 always (coords ~N(0,1))

// NN: PP=8 preds/thread, pred-chunk 2048 (4 pc) x gt-tile 256 (128 gc) = 512 blocks
#define NN_PP     8
#define NN_PCH    2048
#define NN_TILE   256
#define NN_NGC    128
#define NN_BLOCKS 512

// REP: PP=4, pred sub-chunk 1024 (8 s) x self-tile 256 (32 t) = 256 blocks
#define RP_PP     4
#define RP_PCH    1024
#define RP_TILE   256
#define RP_NT     32
#define RP_BLOCKS 256

// ws: u64 nnmax[128][8192] (8MB) | f32 repchunk[32][8192] (1MB) | f32 partials[64][3]
// (ws_size observed = 268 MB via harness poison fill; 9.1 MB needed)
#define OFF_REP  (NN_NGC * N_PRED * 8)
#define OFF_PART (OFF_REP + RP_NT * N_PRED * 4)

__device__ __forceinline__ v2f pk_fma(v2f a, v2f b, v2f c) {
    v2f d;
    asm("v_pk_fma_f32 %0, %1, %2, %3" : "=v"(d) : "v"(a), "v"(b), "v"(c));
    return d;
}
__device__ __forceinline__ float max3f(float a, float b, float c) {
    float d;
    asm("v_max3_f32 %0, %1, %2, %3" : "=v"(d) : "v"(a), "v"(b), "v"(c));
    return d;
}

// load 8 consecutive tile points (base kk, 16B-aligned) as 4 v2f per coord
#define LOAD8(kk, gx, gy, gz, gw)                                               \
    {                                                                           \
        const v4f xv0 = *(const v4f*)&sx[kk], xv1 = *(const v4f*)&sx[(kk) + 4]; \
        const v4f yv0 = *(const v4f*)&sy[kk], yv1 = *(const v4f*)&sy[(kk) + 4]; \
        const v4f zv0 = *(const v4f*)&sz[kk], zv1 = *(const v4f*)&sz[(kk) + 4]; \
        const v4f wv0 = *(const v4f*)&sw[kk], wv1 = *(const v4f*)&sw[(kk) + 4]; \
        gx[0] = __builtin_shufflevector(xv0, xv0, 0, 1);                        \
        gx[1] = __builtin_shufflevector(xv0, xv0, 2, 3);                        \
        gx[2] = __builtin_shufflevector(xv1, xv1, 0, 1);                        \
        gx[3] = __builtin_shufflevector(xv1, xv1, 2, 3);                        \
        gy[0] = __builtin_shufflevector(yv0, yv0, 0, 1);                        \
        gy[1] = __builtin_shufflevector(yv0, yv0, 2, 3);                        \
        gy[2] = __builtin_shufflevector(yv1, yv1, 0, 1);                        \
        gy[3] = __builtin_shufflevector(yv1, yv1, 2, 3);                        \
        gz[0] = __builtin_shufflevector(zv0, zv0, 0, 1);                        \
        gz[1] = __builtin_shufflevector(zv0, zv0, 2, 3);                        \
        gz[2] = __builtin_shufflevector(zv1, zv1, 0, 1);                        \
        gz[3] = __builtin_shufflevector(zv1, zv1, 2, 3);                        \
        gw[0] = __builtin_shufflevector(wv0, wv0, 0, 1);                        \
        gw[1] = __builtin_shufflevector(wv0, wv0, 2, 3);                        \
        gw[2] = __builtin_shufflevector(wv1, wv1, 0, 1);                        \
        gw[3] = __builtin_shufflevector(wv1, wv1, 2, 3);                        \
    }

// dot-product h for 8 points against broadcast pred q
#define DOT8(h, gx, gy, gz, gw, q)                                              \
    {                                                                           \
        _Pragma("unroll")                                                       \
        for (int _i = 0; _i < 4; ++_i) {                                        \
            v2f _t = pk_fma(PZ[q], gz[_i], gw[_i]);                             \
            _t = pk_fma(PY[q], gy[_i], _t);                                     \
            h[_i] = pk_fma(PX[q], gx[_i], _t);                                  \
        }                                                                       \
    }

// max of 8 values in h[4] (v2f) -> scalar
#define RED8(out, h)                                                            \
    {                                                                           \
        const float _m0 = max3f(h[0].x, h[0].y, h[1].x);                        \
        const float _m1 = max3f(h[1].y, h[2].x, h[2].y);                        \
        const float _m2 = fmaxf(h[3].x, h[3].y);                                \
        out = max3f(_m0, _m1, _m2);                                             \
    }

// ---- fused NN + repulsion bulk pass: plain coalesced stores, NO atomics ----
__global__ __launch_bounds__(256) void pair_kernel(const float* __restrict__ pred,
                                                   const float* __restrict__ gt,
                                                   unsigned long long* __restrict__ nnmax,
                                                   float* __restrict__ repchunk) {
    __shared__ alignas(16) float sx[NN_TILE], sy[NN_TILE], sz[NN_TILE], sw[NN_TILE];

    if (blockIdx.x < NN_BLOCKS) {
        // ---------- NN: argmax of h = p.g - 0.5|g|^2 + 64, 8-gt-group latch ----------
        const int pc = blockIdx.x >> 7;
        const int gc = blockIdx.x & (NN_NGC - 1);
        const int gbase = gc * NN_TILE;

        {
            const int k = threadIdx.x;               // NN_TILE == BLK
            const int g = gbase + k;
            const float x = gt[g * 6 + 0], y = gt[g * 6 + 1], z = gt[g * 6 + 2];
            sx[k] = x; sy[k] = y; sz[k] = z;
            sw[k] = fmaf(-0.5f, fmaf(z, z, fmaf(y, y, x * x)), HOFF);
        }
        __syncthreads();

        const int pbase = pc * NN_PCH + threadIdx.x;
        v2f PX[NN_PP], PY[NN_PP], PZ[NN_PP];
        float best[NN_PP];
        unsigned bk[NN_PP];
#pragma unroll
        for (int q = 0; q < NN_PP; ++q) {
            const int p = pbase + q * BLK;
            const float x = pred[p * 6 + 0], y = pred[p * 6 + 1], z = pred[p * 6 + 2];
            v2f vx; vx.x = x; vx.y = x; PX[q] = vx;
            v2f vy; vy.x = y; vy.y = y; PY[q] = vy;
            v2f vz; vz.x = z; vz.y = z; PZ[q] = vz;
            best[q] = 0.0f;                          // h > 0 always
            bk[q] = 0u;
        }

#pragma unroll 1
        for (int k = 0; k < NN_TILE; k += 8) {
            v2f gx[4], gy[4], gz[4], gw[4];
            LOAD8(k, gx, gy, gz, gw);
#pragma unroll
            for (int q = 0; q < NN_PP; ++q) {
                v2f h[4];
                DOT8(h, gx, gy, gz, gw, q);
                float gm;
                RED8(gm, h);
                if (gm > best[q]) { best[q] = gm; bk[q] = (unsigned)k; }  // first group wins ties
            }
        }

#pragma unroll
        for (int q = 0; q < NN_PP; ++q) {
            const unsigned gidx = (unsigned)gbase + bk[q];      // 8-aligned group base
            const unsigned long long key =
                ((unsigned long long)__float_as_uint(best[q]) << 32) |
                (unsigned long long)(~gidx);                    // tie -> smaller index
            nnmax[gc * N_PRED + pbase + q * BLK] = key;         // coalesced 512B/wave
        }

    } else {
        // ---------- Repulsion: per-(pred, tile) max of h, j != i. Value only. ----------
        const int rb = blockIdx.x - NN_BLOCKS;
        const int s = rb >> 5;
        const int t = rb & (RP_NT - 1);
        const int tbase = t * RP_TILE;

        {
            const int k = threadIdx.x;               // RP_TILE == BLK
            const int j = tbase + k;
            const float x = pred[j * 6 + 0], y = pred[j * 6 + 1], z = pred[j * 6 + 2];
            sx[k] = x; sy[k] = y; sz[k] = z;
            sw[k] = fmaf(-0.5f, fmaf(z, z, fmaf(y, y, x * x)), HOFF);
        }
        __syncthreads();

        const int pbase = s * RP_PCH + threadIdx.x;
        v2f PX[RP_PP], PY[RP_PP], PZ[RP_PP];
        float best[RP_PP];
        int selfk[RP_PP];
#pragma unroll
        for (int q = 0; q < RP_PP; ++q) {
            const int p = pbase + q * BLK;
            const float x = pred[p * 6 + 0], y = pred[p * 6 + 1], z = pred[p * 6 + 2];
            v2f vx; vx.x = x; vx.y = x; PX[q] = vx;
            v2f vy; vy.x = y; vy.y = y; PY[q] = vy;
            v2f vz; vz.x = z; vz.y = z; PZ[q] = vz;
            best[q] = -3.0e38f;
            selfk[q] = p - tbase;  // in [0,RP_TILE) only for the matching diagonal sub-chunk
        }

        const bool diag = (t >= s * 4) && (t < s * 4 + 4);
        if (diag) {
#pragma unroll 1
            for (int k = 0; k < RP_TILE; k += 8) {
                v2f gx[4], gy[4], gz[4], gw[4];
                LOAD8(k, gx, gy, gz, gw);
#pragma unroll
                for (int q = 0; q < RP_PP; ++q) {
                    v2f h[4];
                    DOT8(h, gx, gy, gz, gw, q);
#pragma unroll
                    for (int i = 0; i < 4; ++i) {
                        const int kb = k + 2 * i;
                        h[i].x = (kb == selfk[q]) ? -3.0e38f : h[i].x;
                        h[i].y = (kb + 1 == selfk[q]) ? -3.0e38f : h[i].y;
                    }
                    float m;
                    RED8(m, h);
                    best[q] = fmaxf(best[q], m);
                }
            }
        } else {
#pragma unroll 1
            for (int k = 0; k < RP_TILE; k += 8) {
                v2f gx[4], gy[4], gz[4], gw[4];
                LOAD8(k, gx, gy, gz, gw);
#pragma unroll
                for (int q = 0; q < RP_PP; ++q) {
                    v2f h[4];
                    DOT8(h, gx, gy, gz, gw, q);
                    float m;
                    RED8(m, h);
                    best[q] = fmaxf(best[q], m);
                }
            }
        }

#pragma unroll
        for (int q = 0; q < RP_PP; ++q)
            repchunk[t * N_PRED + pbase + q * BLK] = best[q];   // coalesced 256B/wave
    }
}

// ---- finalize: u64-max over 128 chunk keys, 8-point exact rescan, losses ----
__global__ __launch_bounds__(128) void finalize_kernel(const float* __restrict__ pred,
                                                       const float* __restrict__ gt,
                                                       const unsigned long long* __restrict__ nnmax,
                                                       const float* __restrict__ repchunk,
                                                       float* __restrict__ partials) {
    const int p = blockIdx.x * 128 + threadIdx.x;
    const float px = pred[p * 6 + 0], py = pred[p * 6 + 1], pz = pred[p * 6 + 2];

    // 1) merge chunk keys (coalesced 512B/wave loads)
    unsigned long long bkey = 0ull;
#pragma unroll 8
    for (int gc = 0; gc < NN_NGC; ++gc) {
        const unsigned long long k = nnmax[gc * N_PRED + p];
        bkey = (k > bkey) ? k : bkey;
    }
    const int gb = (int)(~(unsigned)(bkey & 0xFFFFFFFFull));

    // 2) exact rescan of winning 8-point group (bitwise-identical fma chain;
    //    first strict max = numpy argmin)
    float bh = -3.0e38f;
    int j = gb;
#pragma unroll
    for (int i = 0; i < 8; ++i) {
        const int g = gb + i;
        const float x = gt[g * 6 + 0], y = gt[g * 6 + 1], z = gt[g * 6 + 2];
        const float w = fmaf(-0.5f, fmaf(z, z, fmaf(y, y, x * x)), HOFF);
        const float h = fmaf(px, x, fmaf(py, y, fmaf(pz, z, w)));
        if (h > bh) { bh = h; j = g; }
    }

    const float gx = gt[j * 6 + 0], gy = gt[j * 6 + 1], gz = gt[j * 6 + 2];
    const float dx = px - gx, dy = py - gy, dz = pz - gz;
    float att = dx * dx + dy * dy + dz * dz;

    const float pnx = pred[p * 6 + 3], pny = pred[p * 6 + 4], pnz = pred[p * 6 + 5];
    const float gnx = gt[j * 6 + 3],   gny = gt[j * 6 + 4],   gnz = gt[j * 6 + 5];
    const float pl = fmaxf(sqrtf(pnx * pnx + pny * pny + pnz * pnz), 1e-5f);
    const float gl = fmaxf(sqrtf(gnx * gnx + gny * gny + gnz * gnz), 1e-5f);
    float nrm = 1.0f - (pnx * gnx + pny * gny + pnz * gnz) / (pl * gl);

    // 3) repulsion max (coalesced 256B/wave loads)
    float rm = -3.0e38f;
#pragma unroll 8
    for (int t = 0; t < RP_NT; ++t)
        rm = fmaxf(rm, repchunk[t * N_PRED + p]);

    // min d^2 = |p|^2 + 2*HOFF - 2*h_max
    const float pp2 = px * px + py * py + pz * pz;
    float d2 = fmaf(-2.0f, rm, pp2 + 2.0f * HOFF);
    d2 = fmaxf(d2, 0.0f);
    const float xa = 100.0f * (0.3f - sqrtf(d2));
    const float sp = fmaxf(xa, 0.0f) + log1pf(expf(-fabsf(xa)));
    float rep = sp * sp;

#pragma unroll
    for (int off = 32; off > 0; off >>= 1) {
        att += __shfl_down(att, off, 64);
        nrm += __shfl_down(nrm, off, 64);
        rep += __shfl_down(rep, off, 64);
    }

    __shared__ float red[2][3];
    const int wave = threadIdx.x >> 6;
    const int lane = threadIdx.x & 63;
    if (lane == 0) { red[wave][0] = att; red[wave][1] = nrm; red[wave][2] = rep; }
    __syncthreads();
    if (threadIdx.x < 3)
        partials[blockIdx.x * 3 + threadIdx.x] = red[0][threadIdx.x] + red[1][threadIdx.x];
}

__global__ void combine_kernel(const float* __restrict__ partials, float* __restrict__ out) {
    const int lane = threadIdx.x;                    // 64 threads, 64 partial rows
    float a = partials[lane * 3 + 0];
    float n = partials[lane * 3 + 1];
    float r = partials[lane * 3 + 2];
#pragma unroll
    for (int off = 32; off > 0; off >>= 1) {
        a += __shfl_down(a, off, 64);
        n += __shfl_down(n, off, 64);
        r += __shfl_down(r, off, 64);
    }
    if (lane == 0)
        out[0] = a / (float)(N_PRED * 3) + r / (float)N_PRED + 10.0f * (n / (float)N_PRED);
}

extern "C" void kernel_launch(void* const* d_in, const int* in_sizes, int n_in,
                              void* d_out, int out_size, void* d_ws, size_t ws_size,
                              hipStream_t stream) {
    const float* pred = (const float*)d_in[0];   // (8192, 6)
    const float* gt   = (const float*)d_in[3];   // (32768, 6)
    float* out = (float*)d_out;
    char* ws = (char*)d_ws;

    unsigned long long* nnmax = (unsigned long long*)ws;      // 8 MB
    float* repchunk = (float*)(ws + OFF_REP);                 // 1 MB
    float* partials = (float*)(ws + OFF_PART);                // 64*3 floats

    pair_kernel<<<NN_BLOCKS + RP_BLOCKS, BLK, 0, stream>>>(pred, gt, nnmax, repchunk);
    finalize_kernel<<<N_PRED / 128, 128, 0, stream>>>(pred, gt, nnmax, repchunk, partials);
    combine_kernel<<<1, 64, 0, stream>>>(partials, out);
}